// Round 8
// baseline (430.834 us; speedup 1.0000x reference)
//
#include <hip/hip_runtime.h>
#include <hip/hip_bf16.h>
#include <math.h>

#define EPS 1e-6f

constexpr int D  = 512;
constexpr int BM = 128;
constexpr int BN = 128;

typedef __attribute__((ext_vector_type(8))) short  short8;
typedef __attribute__((ext_vector_type(4))) float  floatx4;

__device__ inline unsigned short f2bf(float f) {
  union { __hip_bfloat16 h; unsigned short u; } cvt;
  cvt.h = __float2bfloat16(f);
  return cvt.u;
}

// ---------------- prep: fp32 -> bf16 (norm-folded) + ||x||^(-1/2) ----------
// HW-validated (R6/R7, absmax 0.03125). Rows pre-scaled by ||row||^(-1/2)
// before the bf16 cast -> GEMM is scale-free.
__global__ __launch_bounds__(256) void prep_kernel(
    const float* __restrict__ src, __hip_bfloat16* __restrict__ dst,
    float* __restrict__ isn, const int* __restrict__ nrmflag, int nrows) {
  const int lane = threadIdx.x & 63;
  const int row  = blockIdx.x * 4 + (threadIdx.x >> 6);
  if (row >= nrows) return;

  const float4* p4 = (const float4*)(src + (size_t)row * D);
  const float4 v1 = p4[lane];
  const float4 v2 = p4[lane + 64];

  float ss = v1.x * v1.x + v1.y * v1.y + v1.z * v1.z + v1.w * v1.w
           + v2.x * v2.x + v2.y * v2.y + v2.z * v2.z + v2.w * v2.w;
  #pragma unroll
  for (int o = 32; o > 0; o >>= 1) ss += __shfl_xor(ss, o);   // all lanes get ss

  const float s4 = rsqrtf(sqrtf(ss));        // ss^(-1/4) = ||row||^(-1/2)
  if (lane == 0) isn[row] = s4;              // kept for fallback path

  if (dst != nullptr) {
    const float s = (*nrmflag) ? s4 : 1.0f;
    ushort4 u1, u2;
    u1.x = f2bf(v1.x * s); u1.y = f2bf(v1.y * s);
    u1.z = f2bf(v1.z * s); u1.w = f2bf(v1.w * s);
    u2.x = f2bf(v2.x * s); u2.y = f2bf(v2.y * s);
    u2.z = f2bf(v2.z * s); u2.w = f2bf(v2.w * s);
    ushort4* drow = (ushort4*)(dst + (size_t)row * D);
    drow[lane]      = u1;
    drow[lane + 64] = u2;
  }
}

// ---------------- main bf16 MFMA GEMM, C = A * B^T (R7, byte-identical) ----
// DIAGNOSTIC ROUND: this kernel is launched TWICE (scratch C in ws, then real
// C) so its ~160 us dispatches rank above the ~165 us harness fills in the
// rocprof top-5 and we finally get its PMC row (MfmaUtil / FETCH_SIZE /
// VALUBusy / SQ_LDS_BANK_CONFLICT / Occupancy). No kernel changes.
__global__ __launch_bounds__(256) void gemm_bt_kernel(
    const __hip_bfloat16* __restrict__ A, const __hip_bfloat16* __restrict__ B,
    float* __restrict__ C, int N, int M) {
  __shared__ __align__(16) __hip_bfloat16 sA[2][BM * 32];   // 16 KiB
  __shared__ __align__(16) __hip_bfloat16 sB[2][BN * 32];   // 16 KiB

  const int t    = threadIdx.x;
  const int w    = t >> 6;
  const int lane = t & 63;
  const int wm   = w & 1;        // wave row (0..1)
  const int wn   = w >> 1;       // wave col (0..1)

  // XCD band swizzle (bijective; requires gridDim.x % 8 == 0)
  size_t rowA0, rowB0;
  {
    const int gx   = (int)gridDim.x;
    const int orig = (int)(blockIdx.y * gridDim.x + blockIdx.x);
    if ((gx & 7) == 0) {
      const int bandw = gx >> 3;           // A-rows per XCD band
      const int xcd = orig & 7;            // HW round-robins wg->XCD by id
      const int loc = orig >> 3;
      const int ir  = xcd * bandw + (loc % bandw);
      const int ic  = loc / bandw;
      rowA0 = (size_t)ir * BM;
      rowB0 = (size_t)ic * BN;
    } else {
      rowA0 = (size_t)blockIdx.x * BM;
      rowB0 = (size_t)blockIdx.y * BN;
    }
  }

  floatx4 acc[4][4];
  #pragma unroll
  for (int i = 0; i < 4; ++i)
    #pragma unroll
    for (int j = 0; j < 4; ++j) acc[i][j] = (floatx4){0.f, 0.f, 0.f, 0.f};

  // staging: one wave instr = 1 KiB = 16 rows x 64B. lane -> row lane/4,
  // 16B piece (lane%4) of the 64B (=32 bf16) row chunk.
  const int ldRow = lane >> 2;           // 0..15
  const int ldCol = (lane & 3) * 8;      // bf16: 0,8,16,24
  // fragment geometry: A[m=lane&15][k=(lane>>4)*8 + j]
  const int fr = lane & 15;
  const int fq = (lane >> 4) * 8;

  const __hip_bfloat16* gA0 = A + (rowA0 + (size_t)ldRow) * D + ldCol;
  const __hip_bfloat16* gB0 = B + (rowB0 + (size_t)ldRow) * D + ldCol;

  for (int k0 = 0; k0 < D; k0 += 64) {
    #pragma unroll
    for (int h = 0; h < 2; ++h) {
      const int kc = k0 + h * 32;
      #pragma unroll
      for (int j = 0; j < 2; ++j) {
        const int c = w * 2 + j;           // chunk 0..7, wave-uniform
        __builtin_amdgcn_global_load_lds(
            (const __attribute__((address_space(1))) void*)(gA0 + (size_t)(c * 16) * D + kc),
            (__attribute__((address_space(3))) void*)(&sA[h][c * 512]), 16, 0, 0);
        __builtin_amdgcn_global_load_lds(
            (const __attribute__((address_space(1))) void*)(gB0 + (size_t)(c * 16) * D + kc),
            (__attribute__((address_space(3))) void*)(&sB[h][c * 512]), 16, 0, 0);
      }
    }
    __syncthreads();   // drains vmcnt(0): both k-half tiles visible

    #pragma unroll
    for (int h = 0; h < 2; ++h) {
      short8 af[4], bf[4];
      #pragma unroll
      for (int i = 0; i < 4; ++i) {
        af[i] = *(const short8*)(&sA[h][(wm * 64 + i * 16 + fr) * 32 + fq]);
        bf[i] = *(const short8*)(&sB[h][(wn * 64 + i * 16 + fr) * 32 + fq]);
      }
      #pragma unroll
      for (int i = 0; i < 4; ++i)
        #pragma unroll
        for (int j = 0; j < 4; ++j)
          acc[i][j] = __builtin_amdgcn_mfma_f32_16x16x32_bf16(af[i], bf[j], acc[i][j], 0, 0, 0);
    }
    __syncthreads();
  }

  // epilogue: scale-free, nt stores.
  // C/D layout col=lane&15, row=(lane>>4)*4+reg  [m89/m91-verified]
  const int cq = lane >> 4;   // 0..3
  const int cc = lane & 15;

  #pragma unroll
  for (int i = 0; i < 4; ++i) {
    const size_t rbase = rowA0 + wm * 64 + i * 16 + cq * 4;
    #pragma unroll
    for (int r = 0; r < 4; ++r) {
      float* crow = C + (rbase + r) * (size_t)M + rowB0 + wn * 64 + cc;
      #pragma unroll
      for (int j = 0; j < 4; ++j)
        __builtin_nontemporal_store(acc[i][j][r], crow + j * 16);
    }
  }
}

// ---------------- correctness fallback (fp32, used only if !fast) ----------
__global__ __launch_bounds__(256) void fb_gemm(
    const float* __restrict__ A, const float* __restrict__ B,
    const float* __restrict__ ia, const float* __restrict__ ib,
    const int* __restrict__ nrmflag, float* __restrict__ C, int N, int M) {
  __shared__ float sA[32][33];
  __shared__ float sB[32][33];
  const int tx = threadIdx.x & 31;
  const int ty = threadIdx.x >> 5;   // 0..7
  const size_t row0 = (size_t)blockIdx.y * 32;
  const size_t col0 = (size_t)blockIdx.x * 32;
  float acc[4] = {0.f, 0.f, 0.f, 0.f};
  for (int k0 = 0; k0 < D; k0 += 32) {
    #pragma unroll
    for (int r = 0; r < 4; ++r) {
      sA[ty + 8 * r][tx] = A[(row0 + ty + 8 * r) * D + k0 + tx];
      sB[ty + 8 * r][tx] = B[(col0 + ty + 8 * r) * D + k0 + tx];
    }
    __syncthreads();
    #pragma unroll 8
    for (int kk = 0; kk < 32; ++kk) {
      const float bv = sB[tx][kk];
      #pragma unroll
      for (int r = 0; r < 4; ++r) acc[r] += sA[ty + 8 * r][kk] * bv;
    }
    __syncthreads();
  }
  const int nrm  = *nrmflag;
  const float iv = ib[col0 + tx];
  #pragma unroll
  for (int r = 0; r < 4; ++r) {
    const size_t row = row0 + ty + 8 * r;
    float v = acc[r];
    if (nrm) {
      const float denom = 1.0f / (ia[row] * iv) + EPS;  // sqrt(n1*n2)+eps
      v /= denom;
    }
    C[row * (size_t)M + col0 + tx] = v;
  }
}

extern "C" void kernel_launch(void* const* d_in, const int* in_sizes, int n_in,
                              void* d_out, int out_size, void* d_ws, size_t ws_size,
                              hipStream_t stream) {
  const float* A   = (const float*)d_in[0];
  const float* B   = (const float*)d_in[1];
  const int*   nrm = (const int*)d_in[2];
  float*       C   = (float*)d_out;
  const int N = in_sizes[0] / D;
  const int M = in_sizes[1] / D;

  // workspace: [ iaN (N f32) | ibN (M f32) | A_bf16 (N*D) | B_bf16 (M*D) |
  //              C_scratch (N*M f32, DIAGNOSTIC only) ]
  float* iaN = (float*)d_ws;
  float* ibN = iaN + N;
  __hip_bfloat16* Abf = (__hip_bfloat16*)(ibN + M);
  __hip_bfloat16* Bbf = Abf + (size_t)N * D;
  float* Cscr = (float*)(Bbf + (size_t)M * D);

  const size_t need = (size_t)(N + M) * sizeof(float)
                    + (size_t)(N + M) * D * sizeof(__hip_bfloat16);
  const bool fast = (ws_size >= need) && (N % BM == 0) && (M % BN == 0);
  // diagnostic double-launch only if ws also fits a scratch C
  const bool dbl  = fast && (ws_size >= need + (size_t)N * M * sizeof(float));

  prep_kernel<<<(N + 3) / 4, 256, 0, stream>>>(A, fast ? Abf : nullptr, iaN, nrm, N);
  prep_kernel<<<(M + 3) / 4, 256, 0, stream>>>(B, fast ? Bbf : nullptr, ibN, nrm, M);

  if (fast) {
    if (dbl)  // DIAGNOSTIC: identical warm-up launch into ws scratch so the
              // gemm outranks the harness fills in the rocprof top-5
      gemm_bt_kernel<<<dim3(N / BM, M / BN), 256, 0, stream>>>(Abf, Bbf, Cscr, N, M);
    gemm_bt_kernel<<<dim3(N / BM, M / BN), 256, 0, stream>>>(Abf, Bbf, C, N, M);
  } else {
    fb_gemm<<<dim3(M / 32, N / 32), 256, 0, stream>>>(A, B, iaN, ibN, nrm, C, N, M);
  }
}